// Round 7
// baseline (201.664 us; speedup 1.0000x reference)
//
#include <hip/hip_runtime.h>

#define SEQ      512
#define BATCH    64
#define NTAG     64
#define STARTTAG 62
#define ENDTAG   63
#define TILE     4096      // dwords per (t,b) tile
#define NBUF     8
#define HALF     256
#define L2E      1.44269504088896340736f
#define LN2      0.69314718055994530942f

typedef float f32x4 __attribute__((ext_vector_type(4)));
typedef float f32x2 __attribute__((ext_vector_type(2)));
typedef const __attribute__((address_space(1))) unsigned int* gp_t;
typedef __attribute__((address_space(3))) unsigned int* lp_t;

__device__ __forceinline__ void dma16(const float* g, float* l) {
    __builtin_amdgcn_global_load_lds((gp_t)g, (lp_t)l, 16, 0, 0);
}
__device__ __forceinline__ void dma4(const float* g, float* l) {
    __builtin_amdgcn_global_load_lds((gp_t)g, (lp_t)l, 4, 0, 0);
}
__device__ __forceinline__ unsigned lofs(const void* p) {
    return (unsigned)(size_t)(const __attribute__((address_space(3))) char*)p;
}
__device__ __forceinline__ float rfl(float v) {
    return __int_as_float(__builtin_amdgcn_readfirstlane(__float_as_int(v)));
}
__device__ __forceinline__ f32x4 e2v(f32x4 a) {   // exp2(x*log2e) componentwise
    f32x4 r;
    r.x = __builtin_amdgcn_exp2f(a.x * L2E);
    r.y = __builtin_amdgcn_exp2f(a.y * L2E);
    r.z = __builtin_amdgcn_exp2f(a.z * L2E);
    r.w = __builtin_amdgcn_exp2f(a.w * L2E);
    return r;
}

// Untracked LDS ops (inline asm): the compiler's waitcnt pass has no tracked
// consumer of the global_load_lds DMAs -> no forced vmcnt(0) (round-3 lesson).
#define LDSR4(r, a, O) asm volatile("ds_read_b128 %0, %1 offset:" O : "=v"(r) : "v"(a))
#define LDSR2(r, a)    asm volatile("ds_read_b64 %0, %1"  : "=v"(r) : "v"(a))
#define LDSR1(r, a)    asm volatile("ds_read_b32 %0, %1"  : "=v"(r) : "v"(a))
#define LDSW4(a, v)    asm volatile("ds_write_b128 %0, %1" :: "v"(a), "v"(v))
#define LDSW1(a, v)    asm volatile("ds_write_b32 %0, %1"  :: "v"(a), "v"(v))
#define WAITV(N)  do { asm volatile("s_waitcnt vmcnt(" #N ")" ::: "memory"); \
                       __builtin_amdgcn_sched_barrier(0); } while (0)
#define WAITL(N)  do { asm volatile("s_waitcnt lgkmcnt(" #N ")" ::: "memory"); \
                       __builtin_amdgcn_sched_barrier(0); } while (0)

// One chain step. Consumes E-regs EC (tile k, exponentiated last step), produces
// EN (tile k+1) off-chain. Chain itself is: read u + {M0,M1} -> 32 fma ->
// corr-scale -> reduce -> log -> v -> u_next=exp2(v-M_w) -> publish -> barrier.
template<int DIR, bool PRODUCE>
__device__ __forceinline__ void cstep(const float* __restrict__ scores, int b, int k,
    const int (&goff)[8], float* tiles, int ldst0, unsigned laneT,
    unsigned ubase, unsigned mwbase, unsigned uwr, int w, int l,
    f32x4 (&EC)[8], f32x4 (&EN)[8], f32x4& v4, float& v1)
{
    const unsigned parR = (unsigned)(((k + 1) & 1) * 256);
    const unsigned parW = (unsigned)((k & 1) * 256);
    const unsigned mR   = (unsigned)(((k + 1) & 1) * 8);
    const unsigned mW   = (unsigned)((k & 1) * 8);
    f32x2 mm;

    if (DIR == 0) {
        f32x4 u0, u1;
        const unsigned ua = ubase + parR + (unsigned)((l >> 3) * 32);
        LDSR4(u0, ua, "0"); LDSR4(u1, ua, "16");
        LDSR2(mm, mwbase + mR);
        if (PRODUCE) {
            int tt = k + 7; if (tt > HALF - 1) tt = HALF - 1;
            const float* gb = scores + ((size_t)tt * BATCH + b) * TILE;
            float* db = tiles + (size_t)((k + 7) & 7) * TILE + ldst0;
            #pragma unroll
            for (int q = 0; q < 8; ++q) dma16(gb + goff[q], db + 256 * q);
            WAITV(48);
            const unsigned ta = laneT + (unsigned)(((k + 1) & 7) * 16384);
            LDSR4(EN[0], ta, "0");   LDSR4(EN[1], ta, "128");
            LDSR4(EN[2], ta, "256"); LDSR4(EN[3], ta, "384");
            LDSR4(EN[4], ta, "512"); LDSR4(EN[5], ta, "640");
            LDSR4(EN[6], ta, "768"); LDSR4(EN[7], ta, "896");
            WAITL(8);                               // u + mm done; tiles in flight
        } else { WAITL(0); }

        const float us   = (l >= 32) ? mm.y : mm.x;
        const float corr = __builtin_amdgcn_exp2f((us - mm.x) * L2E);
        f32x4 p = EC[0] * u0.x;
        p += EC[1] * u0.y; p += EC[2] * u0.z; p += EC[3] * u0.w;
        p += EC[4] * u1.x; p += EC[5] * u1.y; p += EC[6] * u1.z; p += EC[7] * u1.w;
        p *= corr;

        if (PRODUCE) {
            WAITL(0);                               // tile reads done
            #pragma unroll
            for (int g = 0; g < 8; ++g) EN[g] = e2v(EN[g]);
        }

        p.x += __shfl_xor(p.x, 8);  p.y += __shfl_xor(p.y, 8);
        p.z += __shfl_xor(p.z, 8);  p.w += __shfl_xor(p.w, 8);
        p.x += __shfl_xor(p.x, 16); p.y += __shfl_xor(p.y, 16);
        p.z += __shfl_xor(p.z, 16); p.w += __shfl_xor(p.w, 16);
        p.x += __shfl_xor(p.x, 32); p.y += __shfl_xor(p.y, 32);
        p.z += __shfl_xor(p.z, 32); p.w += __shfl_xor(p.w, 32);

        v4.x = fmaf(__builtin_amdgcn_logf(p.x), LN2, mm.x);
        v4.y = fmaf(__builtin_amdgcn_logf(p.y), LN2, mm.x);
        v4.z = fmaf(__builtin_amdgcn_logf(p.z), LN2, mm.x);
        v4.w = fmaf(__builtin_amdgcn_logf(p.w), LN2, mm.x);
        const float Mn = rfl(v4.x);                 // = v[32w], this wave's shift
        f32x4 u4;
        u4.x = __builtin_amdgcn_exp2f((v4.x - Mn) * L2E);
        u4.y = __builtin_amdgcn_exp2f((v4.y - Mn) * L2E);
        u4.z = __builtin_amdgcn_exp2f((v4.z - Mn) * L2E);
        u4.w = __builtin_amdgcn_exp2f((v4.w - Mn) * L2E);
        if (l < 8)  LDSW4(uwr + parW, u4);
        if (l == 0) LDSW1(mwbase + mW + (unsigned)(w * 4), Mn);
    } else {
        f32x4 u[8];
        const unsigned ua = ubase + parR + (unsigned)((l >> 5) * 128);
        LDSR4(u[0], ua, "0");  LDSR4(u[1], ua, "16");
        LDSR4(u[2], ua, "32"); LDSR4(u[3], ua, "48");
        LDSR4(u[4], ua, "64"); LDSR4(u[5], ua, "80");
        LDSR4(u[6], ua, "96"); LDSR4(u[7], ua, "112");
        LDSR2(mm, mwbase + mR);
        if (PRODUCE) {
            int tt = k + 7; if (tt > HALF - 1) tt = HALF - 1;
            const float* gb = scores + ((size_t)(SEQ - 1 - tt) * BATCH + b) * TILE;
            float* db = tiles + (size_t)((k + 7) & 7) * TILE + ldst0;
            #pragma unroll
            for (int q = 0; q < 8; ++q) dma16(gb + goff[q], db + 256 * q);
            WAITV(48);
            const unsigned ta = laneT + (unsigned)(((k + 1) & 7) * 16384);
            LDSR4(EN[0], ta ^ 0u,   "0"); LDSR4(EN[1], ta ^ 16u,  "0");
            LDSR4(EN[2], ta ^ 32u,  "0"); LDSR4(EN[3], ta ^ 48u,  "0");
            LDSR4(EN[4], ta ^ 64u,  "0"); LDSR4(EN[5], ta ^ 80u,  "0");
            LDSR4(EN[6], ta ^ 96u,  "0"); LDSR4(EN[7], ta ^ 112u, "0");
            WAITL(8);
        } else { WAITL(0); }

        const float us   = (l >= 32) ? mm.y : mm.x;
        const float corr = __builtin_amdgcn_exp2f((us - mm.x) * L2E);
        f32x4 p4 = EC[0] * u[0];
        p4 += EC[1] * u[1]; p4 += EC[2] * u[2]; p4 += EC[3] * u[3];
        p4 += EC[4] * u[4]; p4 += EC[5] * u[5]; p4 += EC[6] * u[6]; p4 += EC[7] * u[7];
        float p = ((p4.x + p4.y) + (p4.z + p4.w)) * corr;

        if (PRODUCE) {
            WAITL(0);
            #pragma unroll
            for (int g = 0; g < 8; ++g) EN[g] = e2v(EN[g]);
        }

        p += __shfl_xor(p, 32);
        v1 = fmaf(__builtin_amdgcn_logf(p), LN2, mm.x);
        const float Mn = rfl(v1);                   // = B[32w]
        const float uu = __builtin_amdgcn_exp2f((v1 - Mn) * L2E);
        if (l < 32) LDSW1(uwr + parW, uu);
        if (l == 0) LDSW1(mwbase + mW + (unsigned)(w * 4), Mn);
    }

    WAITL(0);                                       // publishes drained
    __builtin_amdgcn_s_barrier();
}

template<int DIR>
__device__ void run_half(const float* __restrict__ scores, float* __restrict__ ws,
                         float* tiles, float* uarr, float* mwls, float* initrow,
                         int b, int l, int w)
{
    const unsigned ubase  = lofs(uarr);
    const unsigned mwbase = lofs(mwls);
    int goff[8];
    #pragma unroll
    for (int q = 0; q < 8; ++q) {
        if (DIR == 0) {
            goff[q] = 512 * q + 64 * (l >> 3) + 32 * w + 4 * (l & 7);
        } else {
            const int iloc = 4 * q + (l >> 4);
            const int col  = (4 * (l & 15)) ^ (4 * (iloc & 7));
            goff[q] = (32 * w + iloc) * 64 + col;
        }
    }
    const int ldst0 = w * 2048;

    {   // prologue DMAs: initrow then tiles 1..7
        const float* t0 = scores + ((size_t)(DIR ? (SEQ - 1) : 0) * BATCH + b) * TILE;
        const float* isrc = DIR ? (t0 + l * 64 + ENDTAG) : (t0 + STARTTAG * 64 + l);
        dma4(isrc, initrow + w * 64);
        #pragma unroll
        for (int k = 1; k <= 7; ++k) {
            const int t = DIR ? (SEQ - 1 - k) : k;
            const float* gb = scores + ((size_t)t * BATCH + b) * TILE;
            float* db = tiles + (size_t)(k & 7) * TILE + ldst0;
            #pragma unroll
            for (int q = 0; q < 8; ++q) dma16(gb + goff[q], db + 256 * q);
        }
    }
    WAITV(56);                                     // initrow done
    float iv; LDSR1(iv, lofs(initrow) + (unsigned)(w * 256 + l * 4));
    WAITL(0);
    const float Mi = rfl(iv);                      // init[0], same for both waves
    const float ui = __builtin_amdgcn_exp2f((iv - Mi) * L2E);
    if (w == 0) {
        LDSW1(ubase + (unsigned)(l * 4), ui);      // parity 0, full 64
        if (l == 0) { LDSW1(mwbase + 0u, Mi); LDSW1(mwbase + 4u, Mi); }
    }

    unsigned laneT, uwr;
    const unsigned tbase = lofs(tiles);
    if (DIR == 0) {
        laneT = tbase + (unsigned)(w * 8192 + (l >> 3) * 1024 + (l & 7) * 16);
        uwr   = ubase + (unsigned)((32 * w + 4 * (l & 7)) * 4);
    } else {
        laneT = tbase + (unsigned)(w * 8192 + (l & 31) * 256 + (l >> 5) * 128 + (l & 7) * 16);
        uwr   = ubase + (unsigned)((32 * w + (l & 31)) * 4);
    }

    // EA = exp2(tile1)
    f32x4 EA[8], EB[8];
    WAITV(48);                                     // tile 1 done
    {
        const unsigned ta = laneT + 16384u;        // slot 1
        if (DIR == 0) {
            LDSR4(EA[0], ta, "0");   LDSR4(EA[1], ta, "128");
            LDSR4(EA[2], ta, "256"); LDSR4(EA[3], ta, "384");
            LDSR4(EA[4], ta, "512"); LDSR4(EA[5], ta, "640");
            LDSR4(EA[6], ta, "768"); LDSR4(EA[7], ta, "896");
        } else {
            LDSR4(EA[0], ta ^ 0u,   "0"); LDSR4(EA[1], ta ^ 16u,  "0");
            LDSR4(EA[2], ta ^ 32u,  "0"); LDSR4(EA[3], ta ^ 48u,  "0");
            LDSR4(EA[4], ta ^ 64u,  "0"); LDSR4(EA[5], ta ^ 80u,  "0");
            LDSR4(EA[6], ta ^ 96u,  "0"); LDSR4(EA[7], ta ^ 112u, "0");
        }
    }
    WAITL(0);
    #pragma unroll
    for (int g = 0; g < 8; ++g) EA[g] = e2v(EA[g]);
    __builtin_amdgcn_s_barrier();                  // u/M parity0 published

    f32x4 v4 = {0.f, 0.f, 0.f, 0.f};
    float v1 = 0.f;

    for (int k = 1; k < HALF - 1; k += 2) {
        cstep<DIR, true>(scores, b, k,     goff, tiles, ldst0, laneT,
                         ubase, mwbase, uwr, w, l, EA, EB, v4, v1);
        cstep<DIR, true>(scores, b, k + 1, goff, tiles, ldst0, laneT,
                         ubase, mwbase, uwr, w, l, EB, EA, v4, v1);
    }
    cstep<DIR, false>(scores, b, HALF - 1, goff, tiles, ldst0, laneT,
                      ubase, mwbase, uwr, w, l, EA, EB, v4, v1);

    WAITV(0);                                      // drain tail dummy DMAs
    if (DIR == 0) {
        if (l < 8)
            *(f32x4*)(ws + (size_t)b * 64 + 32 * w + 4 * (l & 7)) = v4;
    } else {
        if (l < 32)
            ws[(size_t)BATCH * NTAG + (size_t)b * 64 + 32 * w + l] = v1;
    }
}

// L2-warmer (round 6): streams chain (b,dir) tiles into throwaway LDS scratch.
__device__ void run_warm(const float* __restrict__ scores, float* tiles,
                         int b, int dir, int l, int w)
{
    const int g0 = 2048 * w;
    float* db = tiles + g0;
    for (int k = 8; k < HALF; ++k) {
        const int t = dir ? (SEQ - 1 - k) : k;
        const float* gb = scores + ((size_t)t * BATCH + b) * TILE + g0 + 4 * l;
        #pragma unroll
        for (int q = 0; q < 8; ++q) dma16(gb + 256 * q, db + 256 * q);
        WAITV(47);
    }
    WAITV(0);
}

__global__ __launch_bounds__(128, 1)
void crf_half_kernel(const float* __restrict__ scores, float* __restrict__ ws)
{
    __shared__ __align__(128) float tiles[NBUF * TILE];   // 128 KiB ring
    __shared__ __align__(128) float uarr[2 * NTAG];       // u = exp(v - M_w), dbuf
    __shared__ __align__(16)  float mwls[4];              // {M0,M1} per parity
    __shared__ __align__(16)  float initrow[2 * NTAG];
    const int tid = (int)threadIdx.x;
    const int l = tid & 63, w = tid >> 6;
    const int bid = (int)blockIdx.x;
    if (bid < 2 * BATCH) {
        const int b = bid >> 1, dir = bid & 1;
        if (dir == 0) run_half<0>(scores, ws, tiles, uarr, mwls, initrow, b, l, w);
        else          run_half<1>(scores, ws, tiles, uarr, mwls, initrow, b, l, w);
    } else {
        const int cid = bid - 2 * BATCH;   // bid%8 == cid%8 -> same XCD (advisory)
        run_warm(scores, tiles, cid >> 1, cid & 1, l, w);
    }
}

__global__ __launch_bounds__(64, 1)
void crf_combine_kernel(const float* __restrict__ scores,
                        const int* __restrict__ target,
                        const int* __restrict__ mask,
                        const float* __restrict__ ws,
                        float* __restrict__ out)
{
    const int b = (int)blockIdx.x, l = (int)threadIdx.x;

    const float s = ws[(size_t)b * NTAG + l]
                  + ws[(size_t)BATCH * NTAG + (size_t)b * NTAG + l];
    float m = s;
    #pragma unroll
    for (int d = 1; d < 64; d <<= 1) m = fmaxf(m, __shfl_xor(m, d, 64));
    float e = __builtin_amdgcn_exp2f((s - m) * L2E);
    #pragma unroll
    for (int d = 1; d < 64; d <<= 1) e += __shfl_xor(e, d, 64);
    const float den = fmaf(__builtin_amdgcn_logf(e), LN2, m);

    float num = 0.f;
    #pragma unroll
    for (int r = 0; r < 8; ++r) {
        const size_t tb = (size_t)(r * 64 + l) * BATCH + b;
        const int tv = target[tb];
        num += (float)mask[tb] * scores[tb * (size_t)TILE + tv];
    }
    #pragma unroll
    for (int d = 1; d < 64; d <<= 1) num += __shfl_xor(num, d, 64);

    if (l == 0) out[b] = (den - num) * (1.0f / BATCH);
}

extern "C" void kernel_launch(void* const* d_in, const int* in_sizes, int n_in,
                              void* d_out, int out_size, void* d_ws, size_t ws_size,
                              hipStream_t stream) {
    const float* scores = (const float*)d_in[0];
    const int*   target = (const int*)d_in[1];
    const int*   mask   = (const int*)d_in[2];
    float*       out    = (float*)d_out;
    float*       ws     = (float*)d_ws;
    (void)in_sizes; (void)n_in; (void)out_size; (void)ws_size;
    hipLaunchKernelGGL(crf_half_kernel, dim3(4 * BATCH), dim3(128), 0, stream,
                       scores, ws);
    hipLaunchKernelGGL(crf_combine_kernel, dim3(BATCH), dim3(64), 0, stream,
                       scores, target, mask, ws, out);
}

// Round 9
// 171.161 us; speedup vs baseline: 1.1782x; 1.1782x over previous
//
#include <hip/hip_runtime.h>

#define SEQ      512
#define BATCH    64
#define NTAG     64
#define STARTTAG 62
#define ENDTAG   63
#define TILE     4096
#define L2E      1.44269504088896340736f
#define LN2      0.69314718055994530942f
#define ESH      7.0f     // fold 2^-7 per-step rescale into exp

typedef float f32x4 __attribute__((ext_vector_type(4)));
typedef short s16x8 __attribute__((ext_vector_type(8)));
typedef int   i32x2 __attribute__((ext_vector_type(2)));
typedef int   i32x4 __attribute__((ext_vector_type(4)));

__device__ __forceinline__ unsigned lofs(const void* p) {
    return (unsigned)(size_t)(const __attribute__((address_space(3))) char*)p;
}
#define LDSW2(a, v) asm volatile("ds_write_b64 %0, %1" :: "v"(a), "v"(v))
#define LDSW1(a, v) asm volatile("ds_write_b32 %0, %1" :: "v"(a), "v"(v))
#define LDSR2(r, a) asm volatile("ds_read_b64 %0, %1" : "=v"(r) : "v"(a))
#define WAITL0() do { asm volatile("s_waitcnt lgkmcnt(0)" ::: "memory"); \
                      __builtin_amdgcn_sched_barrier(0); } while (0)

__device__ __forceinline__ unsigned cvtpk(float lo, float hi) {
    unsigned r;
    asm("v_cvt_pk_bf16_f32 %0, %1, %2" : "=v"(r) : "v"(lo), "v"(hi));
    return r;
}
__device__ __forceinline__ s16x8 mk8(i32x2 a, i32x2 b) {
    union { i32x4 i; s16x8 h; } u;
    u.i.x = a.x; u.i.y = a.y; u.i.z = b.x; u.i.w = b.y;
    return u.h;
}

// Segment kernel: block = (batch b, segment sgi). 256 thr = 4 waves.
// Serially folds NST=SEQ/SPB tiles into R (64x64 fp32 in MFMA accs):
//   R <- R * E_t,  E_t = exp(s_t - 7*ln2)   (2^-7 folded into exp arg)
// Wave w owns R rows [16w,16w+16). A-frags round-trip through wave-PRIVATE
// Rbuf (bf16, XOR-swizzled). E goes to double-buffered swizzled LDS (bf16).
// Tiles load straight to registers (tracked loads, 1-tile prefetch).
// Output: ws[(b*SPB+sgi)*4096 + row*64+col] = ln(R[row][col]) + NST*7*ln2.
template<int SPB>
__global__ __launch_bounds__(256, 2)
void crf_seg(const float* __restrict__ scores, float* __restrict__ ws)
{
    constexpr int NST = SEQ / SPB;
    __shared__ __align__(16) unsigned short ETs[2][NTAG * NTAG]; // 16 KB dbuf
    __shared__ __align__(16) unsigned short Rb[4][16 * NTAG];    // 8 KB, per-wave

    const int tid = (int)threadIdx.x;
    const int l = tid & 63, w = tid >> 6;
    const int b   = (int)blockIdx.x / SPB;
    const int sgi = (int)blockIdx.x % SPB;
    const int t0  = sgi * NST;
    const int g   = l >> 4;                 // lane group
    const int c   = l & 15;

    const int i0 = 4 * (tid >> 4);          // subtile rows  (16w + 4g)
    const int j0 = 4 * (tid & 15);          // subtile cols  (4c)

    const unsigned ET0 = lofs(ETs), ET1 = ET0 + 8192;
    const unsigned RbW = lofs(Rb) + (unsigned)(w * 2048);

    // identity init of private Rbuf (local rows 0..15 = abs rows 16w+rr)
    if (l < 32) {
        const int c0 = 2 * l;
        #pragma unroll
        for (int rr = 0; rr < 16; ++rr) {
            unsigned val = ((c0 == 16 * w + rr) ? 0x3F80u : 0u)
                         | (((c0 + 1 == 16 * w + rr) ? 0x3F80u : 0u) << 16);
            LDSW1(RbW + (unsigned)(rr * 128 + ((c0 * 2) ^ (rr << 3))), val);
        }
    }
    WAITL0();

    f32x4 acc[4];
    #pragma unroll
    for (int nt = 0; nt < 4; ++nt) acc[nt] = (f32x4){0.f, 0.f, 0.f, 0.f};

    // prologue: tile t0 -> Ta
    f32x4 Ta[4], Tb[4];
    {
        const float* gp = scores + ((size_t)(t0 * BATCH + b)) * TILE + (i0 * 64 + j0);
        #pragma unroll
        for (int ir = 0; ir < 4; ++ir) Ta[ir] = *(const f32x4*)(gp + ir * 64);
    }

    #define STEP(K, TC, TN) do {                                              \
        const int k_ = (K);                                                   \
        { /* issue next tile's loads early */                                 \
            int tt = t0 + ((k_ + 1 < NST) ? k_ + 1 : NST - 1);                \
            const float* gp = scores + ((size_t)(tt * BATCH + b)) * TILE      \
                              + (i0 * 64 + j0);                               \
            _Pragma("unroll")                                                 \
            for (int ir = 0; ir < 4; ++ir) TN[ir] = *(const f32x4*)(gp + ir*64);\
            __builtin_amdgcn_sched_barrier(0);                                \
        }                                                                     \
        const unsigned ep = (k_ & 1) ? ET1 : ET0;                             \
        { /* E-production: exp + pack + swizzled store */                     \
            f32x4 Ev[4];                                                      \
            _Pragma("unroll")                                                 \
            for (int ir = 0; ir < 4; ++ir) {                                  \
                Ev[ir].x = __builtin_amdgcn_exp2f(fmaf(TC[ir].x, L2E, -ESH)); \
                Ev[ir].y = __builtin_amdgcn_exp2f(fmaf(TC[ir].y, L2E, -ESH)); \
                Ev[ir].z = __builtin_amdgcn_exp2f(fmaf(TC[ir].z, L2E, -ESH)); \
                Ev[ir].w = __builtin_amdgcn_exp2f(fmaf(TC[ir].w, L2E, -ESH)); \
            }                                                                 \
            _Pragma("unroll")                                                 \
            for (int jc = 0; jc < 4; ++jc) {                                  \
                i32x2 wv;                                                     \
                wv.x = (int)cvtpk(Ev[0][jc], Ev[1][jc]);                      \
                wv.y = (int)cvtpk(Ev[2][jc], Ev[3][jc]);                      \
                const int ja = j0 + jc;                                       \
                LDSW2(ep + (unsigned)(ja * 128 + ((i0 * 2) ^ ((ja & 15) << 3))), wv); \
            }                                                                 \
        }                                                                     \
        WAITL0();                                                             \
        __builtin_amdgcn_s_barrier();                                         \
        { /* fragment reads + MFMA + publish */                               \
            i32x2 ar[2][2], br[2][4][2];                                      \
            _Pragma("unroll")                                                 \
            for (int kt = 0; kt < 2; ++kt)                                    \
                _Pragma("unroll")                                             \
                for (int h = 0; h < 2; ++h)                                   \
                    LDSR2(ar[kt][h], RbW + (unsigned)(c * 128 +               \
                          ((64 * kt + 16 * g + 8 * h) ^ (c << 3))));          \
            _Pragma("unroll")                                                 \
            for (int kt = 0; kt < 2; ++kt)                                    \
                _Pragma("unroll")                                             \
                for (int nt = 0; nt < 4; ++nt) {                              \
                    const int n = 16 * nt + c;                                \
                    _Pragma("unroll")                                         \
                    for (int h = 0; h < 2; ++h)                               \
                        LDSR2(br[kt][nt][h], ep + (unsigned)(n * 128 +        \
                              ((64 * kt + 16 * g + 8 * h) ^ ((n & 15) << 3))));\
                }                                                             \
            WAITL0();                                                         \
            /* BUG FIX (round 8): fresh accumulator every step - R_new = R*E, */ \
            /* not R + R*E. Zero C-in before the kt accumulation.             */ \
            _Pragma("unroll")                                                 \
            for (int nt = 0; nt < 4; ++nt) acc[nt] = (f32x4){0.f,0.f,0.f,0.f};\
            _Pragma("unroll")                                                 \
            for (int kt = 0; kt < 2; ++kt) {                                  \
                const s16x8 af = mk8(ar[kt][0], ar[kt][1]);                   \
                _Pragma("unroll")                                             \
                for (int nt = 0; nt < 4; ++nt)                                \
                    acc[nt] = __builtin_amdgcn_mfma_f32_16x16x32_bf16(        \
                        af, mk8(br[kt][nt][0], br[kt][nt][1]), acc[nt], 0, 0, 0); \
            }                                                                 \
            _Pragma("unroll")                                                 \
            for (int nt = 0; nt < 4; ++nt)                                    \
                _Pragma("unroll")                                             \
                for (int r = 0; r < 4; ++r) {                                 \
                    const float v = acc[nt][r];                               \
                    const float vp = __shfl_xor(v, 1);                        \
                    const unsigned pw = (l & 1) ? cvtpk(vp, v) : cvtpk(v, vp);\
                    const int rl = 4 * g + r;                                 \
                    if ((l & 1) == 0)                                         \
                        LDSW1(RbW + (unsigned)(rl * 128 +                     \
                              (((16 * nt + (l & 14)) * 2) ^ (rl << 3))), pw); \
                }                                                             \
            WAITL0();                                                         \
        }                                                                     \
    } while (0)

    for (int k = 0; k < NST; k += 2) {
        STEP(k,     Ta, Tb);
        STEP(k + 1, Tb, Ta);
    }
    #undef STEP

    // epilogue: L = ln(acc) + NST*7*ln2 -> ws (fp32, log space)
    const float OFF = (float)NST * ESH * LN2;
    float* wp = ws + ((size_t)(b * SPB + sgi)) * 4096;
    #pragma unroll
    for (int nt = 0; nt < 4; ++nt)
        #pragma unroll
        for (int r = 0; r < 4; ++r) {
            const int row = 16 * w + 4 * g + r;
            const int col = 16 * nt + c;
            wp[row * 64 + col] = fmaf(__builtin_amdgcn_logf(acc[nt][r]), LN2, OFF);
        }
}

// Combine: per batch, chain a (log-vec, init onehot START) through SPB
// log-matvecs, then den = a[END]; numerator gather; out = (den-num)/64.
template<int SPB>
__global__ __launch_bounds__(64, 1)
void crf_comb(const float* __restrict__ scores, const int* __restrict__ target,
              const int* __restrict__ mask, const float* __restrict__ ws,
              float* __restrict__ out)
{
    __shared__ float Ls[64][65];
    __shared__ float av[64];
    const int b = (int)blockIdx.x, l = (int)threadIdx.x;

    float a = (l == STARTTAG) ? 0.f : -1e30f;
    for (int g = 0; g < SPB; ++g) {
        const float* Lp = ws + ((size_t)(b * SPB + g)) * 4096 + l * 64;
        #pragma unroll
        for (int c4 = 0; c4 < 16; ++c4)
            *(f32x4*)&Ls[l][4 * c4] = *(const f32x4*)(Lp + 4 * c4);
        av[l] = a;
        __syncthreads();
        float M = -3.0e38f;
        #pragma unroll 8
        for (int m = 0; m < 64; ++m) M = fmaxf(M, av[m] + Ls[m][l]);
        float p = 0.f;
        #pragma unroll 8
        for (int m = 0; m < 64; ++m)
            p += __builtin_amdgcn_exp2f((av[m] + Ls[m][l] - M) * L2E);
        a = fmaf(__builtin_amdgcn_logf(p), LN2, M);
        __syncthreads();
    }
    const float den = __shfl(a, ENDTAG, 64);

    float num = 0.f;
    #pragma unroll
    for (int r = 0; r < 8; ++r) {
        const size_t tb = (size_t)(r * 64 + l) * BATCH + b;
        num += (float)mask[tb] * scores[tb * (size_t)TILE + target[tb]];
    }
    #pragma unroll
    for (int d = 1; d < 64; d <<= 1) num += __shfl_xor(num, d, 64);

    if (l == 0) out[b] = (den - num) * (1.0f / BATCH);
}

extern "C" void kernel_launch(void* const* d_in, const int* in_sizes, int n_in,
                              void* d_out, int out_size, void* d_ws, size_t ws_size,
                              hipStream_t stream) {
    const float* scores = (const float*)d_in[0];
    const int*   target = (const int*)d_in[1];
    const int*   mask   = (const int*)d_in[2];
    float*       out    = (float*)d_out;
    float*       ws     = (float*)d_ws;
    (void)in_sizes; (void)n_in; (void)out_size;

    const size_t need8 = (size_t)BATCH * 8 * 4096 * 4;
    const size_t need4 = (size_t)BATCH * 4 * 4096 * 4;
    if (ws_size >= need8) {
        hipLaunchKernelGGL(crf_seg<8>,  dim3(BATCH * 8), dim3(256), 0, stream, scores, ws);
        hipLaunchKernelGGL(crf_comb<8>, dim3(BATCH),     dim3(64),  0, stream,
                           scores, target, mask, ws, out);
    } else if (ws_size >= need4) {
        hipLaunchKernelGGL(crf_seg<4>,  dim3(BATCH * 4), dim3(256), 0, stream, scores, ws);
        hipLaunchKernelGGL(crf_comb<4>, dim3(BATCH),     dim3(64),  0, stream,
                           scores, target, mask, ws, out);
    } else {
        hipLaunchKernelGGL(crf_seg<2>,  dim3(BATCH * 2), dim3(256), 0, stream, scores, ws);
        hipLaunchKernelGGL(crf_comb<2>, dim3(BATCH),     dim3(64),  0, stream,
                           scores, target, mask, ws, out);
    }
}